// Round 6
// baseline (3031.884 us; speedup 1.0000x reference)
//
#include <hip/hip_runtime.h>

#define B_   32
#define T_   300
#define C1_  2312
#define O1_  512
#define O2_  512
#define O3_  10
#define M_   (B_*T_)   // 9600
#define KSPLIT_ 1152   // gemm1 K halves: [0,1152) = 72 groups, [1152,2312) = 73 groups

typedef double v2d __attribute__((ext_vector_type(2)));   // clang-native for nontemporal builtins

// ---------------- weight prep (all f64) ----------------

__global__ void calc_f(const float* __restrict__ v, const float* __restrict__ g,
                       double* __restrict__ f, int O, int C) {
    int o = blockIdx.x;
    const float* row = v + (size_t)o * C;
    double s = 0.0;
    for (int c = threadIdx.x; c < C; c += blockDim.x) {
        double x = (double)row[c];
        s += x * x;
    }
    for (int off = 32; off; off >>= 1) s += __shfl_down(s, off);
    __shared__ double wsum[4];
    int lane = threadIdx.x & 63, wv = threadIdx.x >> 6;
    if (lane == 0) wsum[wv] = s;
    __syncthreads();
    if (threadIdx.x == 0) {
        double tot = 0.0;
        for (int i = 0; i < (int)(blockDim.x >> 6); ++i) tot += wsum[i];
        f[o] = (double)g[o] / sqrt(tot);
    }
}

// wt[c*ldo + o] = v[o*C + c] * f[o]   (double)
__global__ void transpose_scale(const float* __restrict__ v, const double* __restrict__ f,
                                double* __restrict__ wt, int O, int C, int ldo) {
    __shared__ double tile[32][33];
    int c0 = blockIdx.x * 32, o0 = blockIdx.y * 32;
    int tx = threadIdx.x, ty = threadIdx.y;
    for (int k = 0; k < 4; ++k) {
        int o = o0 + ty + k * 8, c = c0 + tx;
        double val = 0.0;
        if (o < O && c < C) val = (double)v[(size_t)o * C + c] * f[o];
        tile[ty + k * 8][tx] = val;
    }
    __syncthreads();
    for (int k = 0; k < 4; ++k) {
        int c = c0 + ty + k * 8, o = o0 + tx;
        if (c < C && o < O) wt[(size_t)c * ldo + o] = tile[tx][ty + k * 8];
    }
}

// ---------------- spike -> bitmask precompute ----------------
__global__ void build_bits(const float* __restrict__ X, unsigned* __restrict__ bits) {
    size_t idx = (size_t)blockIdx.x * 256 + threadIdx.x;
    if (idx >= (size_t)B_ * C1_ * 10) return;
    int t32 = (int)(idx % 10);
    size_t bc = idx / 10;
    const float* src = X + bc * T_ + t32 * 32;
    int nq = (t32 == 9) ? 3 : 8;   // 12 or 32 valid t's (T_=300)
    unsigned m = 0;
    for (int q = 0; q < nq; ++q) {
        float4 v = *(const float4*)(src + q * 4);
        if (v.x != 0.f) m |= 1u << (q * 4 + 0);
        if (v.y != 0.f) m |= 1u << (q * 4 + 1);
        if (v.z != 0.f) m |= 1u << (q * 4 + 2);
        if (v.w != 0.f) m |= 1u << (q * 4 + 3);
    }
    bits[idx] = m;
}

// ---------------- GEMM layer 1 v5 (f64 sparse, L2-direct gather, NO LDS/barriers) ----------------
// 4-round evidence: every LDS-staged variant (2-barrier, 4-way split, dbuf)
// pays a per-tile drain tax; VALUBusy ~20%, occupancy <= 38%.  v5 deletes the
// staging: each c-hit reads its W row slice straight from the XCD-pinned L2
// (2x dwordx4 per wave, coalesced 1 KB).  No __syncthreads anywhere; 256-thr
// blocks of 4 independent waves; launch_bounds(256,5) -> ~20 waves/CU TLP.
// Read volume ~6.9 GB ~= previous LDS-read volume, but staging (1.5 GB L2 +
// 1.5 GB LDS writes) and all vmcnt(0) drains vanish.  L2 roofline ~200 us.
// Wave = (b, t-octet, o-half, k-half); c ascending => summation order
// IDENTICAL to round-4 gemm1 (passed, absmax 0.0).  Z stores nontemporal so
// the streamed output doesn't evict the pinned W slice.
__global__ __launch_bounds__(256, 5) void gemm1(const unsigned* __restrict__ Xbits,
                                                const double* __restrict__ Wt,
                                                double* __restrict__ Z0,
                                                double* __restrict__ Z1) {
    int n = blockIdx.x;
    int combo = n & 3;                 // (khalf, ohalf) ; n&7 -> XCD sees ONE slice
    int khalf = combo & 1;
    int o0 = (combo >> 1) * 256;
    int i = n >> 2;                    // 0..319
    int tb = i % 10;                   // 32-t window
    int b = i / 10;
    int tid = threadIdx.x;
    int w = tid >> 6;                  // octet 0..3
    int lane = tid & 63;
    int w8s = __builtin_amdgcn_readfirstlane(w << 3);
    int cbeg = khalf ? KSPLIT_ : 0;
    int cend = khalf ? C1_ : KSPLIT_;
    const int NG = khalf ? 73 : 72;    // 16-c groups
    double* __restrict__ Z = khalf ? Z1 : Z0;
    v2d acc[8][2];                     // [t][o-128-pair]; o = o0 + i2*128 + 2*lane (+0/1)
#pragma unroll
    for (int tj = 0; tj < 8; ++tj)
#pragma unroll
        for (int i2 = 0; i2 < 2; ++i2) { acc[tj][i2][0] = 0.0; acc[tj][i2][1] = 0.0; }
    const unsigned* xbp = Xbits + (size_t)b * C1_ * 10 + tb;

    auto load_m = [&](int c0) -> unsigned {
        int c = c0 + lane;
        return (lane < 16 && c < cend) ? xbp[(size_t)c * 10] : 0u;
    };

    unsigned mval = load_m(cbeg);
    int c0 = cbeg;
    for (int g = 0; g < NG; ++g) {
        unsigned mnext = (g + 1 < NG) ? load_m(c0 + 16) : 0u;
#pragma unroll
        for (int k = 0; k < 16; ++k) {
            unsigned smk = (unsigned)__builtin_amdgcn_readlane((int)mval, k);
            unsigned soct = (smk >> w8s) & 0xffu;
            if (soct) {   // wave-uniform scalar branch
                const v2d* wp = (const v2d*)(Wt + (size_t)(c0 + k) * O1_ + o0);
                v2d wf0 = wp[lane];        // o0 +   2*lane
                v2d wf1 = wp[lane + 64];   // o0 + 128 + 2*lane
#pragma unroll
                for (int tj = 0; tj < 8; ++tj) {
                    if (soct & (1u << tj)) {
                        acc[tj][0] += wf0;
                        acc[tj][1] += wf1;
                    }
                }
            }
        }
        mval = mnext;
        c0 += 16;
    }
#pragma unroll
    for (int tj = 0; tj < 8; ++tj) {
        int t = tb * 32 + w8s + tj;
        if (t < T_) {
            v2d* dst = (v2d*)(Z + ((size_t)b * T_ + t) * O1_ + o0);
            __builtin_nontemporal_store(acc[tj][0], dst + lane);
            __builtin_nontemporal_store(acc[tj][1], dst + lane + 64);
        }
    }
}

// ---------------- GEMM layer 2 v5 (f64 sparse, L2-direct gather, full K) ----------------
// W2 = 2 MB: fully resident in EVERY XCD's L2 -> no K-split, single Z output.
// Same wave template as gemm1; c ascending 0..511 single-sum = round-2's
// validated order on bit-identical s1 bits.  Sbits: [B, 512, 10] u32.
__global__ __launch_bounds__(256, 5) void gemm2s(const unsigned* __restrict__ Sbits,
                                                 const double* __restrict__ Wt,
                                                 double* __restrict__ Z) {
    int n = blockIdx.x;
    int ohalf = n & 1;
    int o0 = ohalf * 256;
    int i = n >> 1;                    // 0..319
    int g4 = i % 10;                   // 4-octet group (mask word index)
    int b = i / 10;
    int tid = threadIdx.x;
    int w = tid >> 6;                  // octet within group, 0..3
    int lane = tid & 63;
    int w8s = __builtin_amdgcn_readfirstlane(w << 3);
    v2d acc[8][2];
#pragma unroll
    for (int tj = 0; tj < 8; ++tj)
#pragma unroll
        for (int i2 = 0; i2 < 2; ++i2) { acc[tj][i2][0] = 0.0; acc[tj][i2][1] = 0.0; }
    const unsigned* xbp = Sbits + (size_t)b * O1_ * 10 + g4;

    auto load_m = [&](int c0) -> unsigned {
        int c = c0 + lane;
        return (lane < 16) ? xbp[(size_t)c * 10] : 0u;
    };

    unsigned mval = load_m(0);
    int c0 = 0;
    for (int g = 0; g < 32; ++g) {
        unsigned mnext = (g + 1 < 32) ? load_m(c0 + 16) : 0u;
#pragma unroll
        for (int k = 0; k < 16; ++k) {
            unsigned smk = (unsigned)__builtin_amdgcn_readlane((int)mval, k);
            unsigned soct = (smk >> w8s) & 0xffu;
            if (soct) {
                const v2d* wp = (const v2d*)(Wt + (size_t)(c0 + k) * O2_ + o0);
                v2d wf0 = wp[lane];
                v2d wf1 = wp[lane + 64];
#pragma unroll
                for (int tj = 0; tj < 8; ++tj) {
                    if (soct & (1u << tj)) {
                        acc[tj][0] += wf0;
                        acc[tj][1] += wf1;
                    }
                }
            }
        }
        mval = mnext;
        c0 += 16;
    }
#pragma unroll
    for (int tj = 0; tj < 8; ++tj) {
        int t = g4 * 32 + w8s + tj;    // word g4 covers t = g4*32 .. +31
        if (t < T_) {
            v2d* dst = (v2d*)(Z + ((size_t)b * T_ + t) * O2_ + o0);
            __builtin_nontemporal_store(acc[tj][0], dst + lane);
            __builtin_nontemporal_store(acc[tj][1], dst + lane + 64);
        }
    }
}

// ---------------- GEMM layer 3 (f64 acc) ----------------
__global__ void gemm3(const float* __restrict__ A,
                      const double* __restrict__ Wt,
                      double* __restrict__ Z) {
    __shared__ double w[512 * 16];
    for (int e = threadIdx.x; e < 4096; e += 256)
        ((double2*)w)[e] = ((const double2*)Wt)[e];
    __syncthreads();
    int m = blockIdx.x * 256 + threadIdx.x;
    if (m >= M_) return;
    double acc[O3_];
#pragma unroll
    for (int o = 0; o < O3_; ++o) acc[o] = 0.0;
    const float4* Ar = (const float4*)(A + (size_t)m * 512);
    for (int cq = 0; cq < 128; ++cq) {
        float4 a = Ar[cq];
        float av[4] = {a.x, a.y, a.z, a.w};
#pragma unroll
        for (int u = 0; u < 4; ++u)
#pragma unroll
            for (int o = 0; o < O3_; ++o) acc[o] += (double)av[u] * w[(cq * 4 + u) * 16 + o];
    }
    double* dst = Z + (size_t)m * 16;
#pragma unroll
    for (int o = 0; o < O3_; ++o) dst[o] = acc[o];
}

// ---------------- LIF scan + delay, layers 1/2 (O=512, f64 state) ----------------
// Zb (2nd K-partial) summed in fixed order if non-null.  Sout / bitsOut each
// optional (layer 1 needs only bits; layer 2 needs only floats).
__global__ void scan12(const double* __restrict__ Za,   // [B, T, 512] f64
                       const double* __restrict__ Zb,   // partial 2 or nullptr
                       const int* __restrict__ delay,   // [512]
                       float* __restrict__ Sout,        // [B, T, 512] f32 or nullptr
                       unsigned* __restrict__ bitsOut,  // [B, 512, 10] u32 or nullptr
                       float* __restrict__ sumOut) {
    int blk = blockIdx.x;
    int o = (blk & 7) * 64 + threadIdx.x;
    int b = blk >> 3;
    size_t base = (size_t)b * T_ * O1_ + o;
    const double* z  = Za + base;
    const double* z2 = Zb ? Zb + base : nullptr;
    float* s = Sout ? Sout + base : nullptr;
    int d = delay[o];
    if (s) for (int t = 0; t < d; ++t) s[(size_t)t * O1_] = 0.f;
    double cur = 0.0, vol = 0.0;
    float cnt = 0.f;
    unsigned bw = 0u;   // running bit word; d<32 so words 0..8 flush in-loop
    for (int t8 = 0; t8 < 296; t8 += 8) {
        double zbuf[8];
#pragma unroll
        for (int u = 0; u < 8; ++u) zbuf[u] = z[(size_t)(t8 + u) * O1_];
        if (z2) {
#pragma unroll
            for (int u = 0; u < 8; ++u) zbuf[u] += z2[(size_t)(t8 + u) * O1_];
        }
#pragma unroll
        for (int u = 0; u < 8; ++u) {
            int t = t8 + u;
            cur = cur * 0.75 + zbuf[u];
            vol = vol * 0.97 + cur;
            float sp = (vol >= 1.25) ? 1.f : 0.f;
            if (sp > 0.f) vol = 0.0;
            int tw = t + d;
            if (tw < T_) {
                if (s) s[(size_t)tw * O1_] = sp;
                cnt += sp;
                if (bitsOut) {
                    if (sp > 0.f) bw |= 1u << (tw & 31);
                    if ((tw & 31) == 31) { bitsOut[((size_t)b * O1_ + o) * 10 + (tw >> 5)] = bw; bw = 0u; }
                }
            }
        }
    }
    {
        double zbuf[4];
#pragma unroll
        for (int u = 0; u < 4; ++u) zbuf[u] = z[(size_t)(296 + u) * O1_];
        if (z2) {
#pragma unroll
            for (int u = 0; u < 4; ++u) zbuf[u] += z2[(size_t)(296 + u) * O1_];
        }
#pragma unroll
        for (int u = 0; u < 4; ++u) {
            int t = 296 + u;
            cur = cur * 0.75 + zbuf[u];
            vol = vol * 0.97 + cur;
            float sp = (vol >= 1.25) ? 1.f : 0.f;
            if (sp > 0.f) vol = 0.0;
            int tw = t + d;
            if (tw < T_) {
                if (s) s[(size_t)tw * O1_] = sp;
                cnt += sp;
                if (bitsOut) {
                    if (sp > 0.f) bw |= 1u << (tw & 31);
                    if ((tw & 31) == 31) { bitsOut[((size_t)b * O1_ + o) * 10 + (tw >> 5)] = bw; bw = 0u; }
                }
            }
        }
    }
    if (bitsOut) bitsOut[((size_t)b * O1_ + o) * 10 + 9] = bw;  // word 9 never flushes in-loop
    for (int off = 32; off; off >>= 1) cnt += __shfl_down(cnt, off);
    if (threadIdx.x == 0) atomicAdd(sumOut, cnt);
}

// ---------------- LIF scan + delay, layer 3 (O=10, f64 state) ----------------
__global__ void scan3(const double* __restrict__ Z3,  // [M, 16] f64
                      const int* __restrict__ d3,     // [10]
                      float* __restrict__ out,        // d_out: [B, 10, 300] f32
                      float* __restrict__ sumOut) {
    __shared__ double zt[T_ * 16];
    int b = blockIdx.x;
    const double2* src = (const double2*)(Z3 + (size_t)b * T_ * 16);
    for (int e = threadIdx.x; e < T_ * 8; e += 64)
        ((double2*)zt)[e] = src[e];
    __syncthreads();
    int o = threadIdx.x;
    if (o < O3_) {
        int d = d3[o];
        float* dst = out + (size_t)b * O3_ * T_ + (size_t)o * T_;
        for (int t = 0; t < d; ++t) dst[t] = 0.f;
        double cur = 0.0, vol = 0.0;
        float cnt = 0.f;
        for (int t = 0; t < T_; ++t) {
            cur = cur * 0.75 + zt[t * 16 + o];
            vol = vol * 0.97 + cur;
            float sp = (vol >= 1.25) ? 1.f : 0.f;
            if (sp > 0.f) vol = 0.0;
            int tw = t + d;
            if (tw < T_) { dst[tw] = sp; cnt += sp; }
        }
        atomicAdd(sumOut, cnt);
    }
}

__global__ void finalize(const float* __restrict__ sums, float* __restrict__ out) {
    if (threadIdx.x == 0) {
        out[0] = (float)((double)sums[0] / (double)(B_ * O1_ * T_));
        out[1] = (float)((double)sums[1] / (double)(B_ * O2_ * T_));
        out[2] = (float)((double)sums[2] / (double)(B_ * O3_ * T_));
    }
}

extern "C" void kernel_launch(void* const* d_in, const int* in_sizes, int n_in,
                              void* d_out, int out_size, void* d_ws, size_t ws_size,
                              hipStream_t stream) {
    const float* spike = (const float*)d_in[0];
    const float* v1 = (const float*)d_in[1];
    const float* g1 = (const float*)d_in[2];
    const float* v2 = (const float*)d_in[3];
    const float* g2 = (const float*)d_in[4];
    const float* v3 = (const float*)d_in[5];
    const float* g3 = (const float*)d_in[6];
    const int* d1 = (const int*)d_in[7];
    const int* d2 = (const int*)d_in[8];
    const int* d3 = (const int*)d_in[9];
    float* out = (float*)d_out;

    // Workspace: ~115 MB.
    double* dw = (double*)d_ws;
    size_t off = 0;
    double* f1  = dw + off; off += 512;
    double* f2  = dw + off; off += 512;
    double* f3  = dw + off; off += 16;
    double* Wt1 = dw + off; off += (size_t)C1_ * O1_;
    double* Wt2 = dw + off; off += 512 * 512;
    double* Wt3 = dw + off; off += 512 * 16;
    double* zA  = dw + off; off += (size_t)M_ * 512;
    double* zB  = dw + off; off += (size_t)M_ * 512;
    double* z3b = dw + off; off += (size_t)M_ * 16;
    float* fw = (float*)(dw + off);
    float* sB    = fw;                                   // f32 spikes, M*512
    float* sums  = fw + (size_t)M_ * 512;                // 4 floats
    unsigned* Xbits = (unsigned*)(fw + (size_t)M_ * 512 + 4);  // B*C1*10 u32
    unsigned* bits2 = Xbits + (size_t)B_ * C1_ * 10;           // B*512*10 u32
    (void)ws_size; (void)out_size; (void)in_sizes; (void)n_in;

    hipMemsetAsync(sums, 0, 4 * sizeof(float), stream);

    build_bits<<<(B_ * C1_ * 10 + 255) / 256, 256, 0, stream>>>(spike, Xbits);

    calc_f<<<512, 256, 0, stream>>>(v1, g1, f1, O1_, C1_);
    calc_f<<<512, 256, 0, stream>>>(v2, g2, f2, O2_, O1_);
    calc_f<<<O3_, 256, 0, stream>>>(v3, g3, f3, O3_, O2_);

    transpose_scale<<<dim3((C1_ + 31) / 32, 16), dim3(32, 8), 0, stream>>>(v1, f1, Wt1, O1_, C1_, O1_);
    transpose_scale<<<dim3(16, 16), dim3(32, 8), 0, stream>>>(v2, f2, Wt2, O2_, O1_, O2_);
    transpose_scale<<<dim3(16, 1), dim3(32, 8), 0, stream>>>(v3, f3, Wt3, O3_, O2_, 16);

    // gemm1 v5: 1280 blocks x 256 thr, L2-direct gather, no barriers
    gemm1<<<1280, 256, 0, stream>>>(Xbits, Wt1, zA, zB);
    // scan12 #1: sum zA+zB, emit ONLY bits (s1 floats are dead)
    scan12<<<256, 64, 0, stream>>>(zA, zB, d1, nullptr, bits2, sums + 0);
    // gemm2s v5: 640 blocks x 256 thr, L2-direct gather, full K, single output
    gemm2s<<<640, 256, 0, stream>>>(bits2, Wt2, zA);
    // scan12 #2: zA only, emit ONLY floats (bits are dead)
    scan12<<<256, 64, 0, stream>>>(zA, nullptr, d2, sB, nullptr, sums + 1);
    gemm3<<<(M_ + 255) / 256, 256, 0, stream>>>(sB, Wt3, z3b);        // z3b = z3
    scan3<<<B_, 64, 0, stream>>>(z3b, d3, out, sums + 2);
    finalize<<<1, 64, 0, stream>>>(sums, out + (size_t)B_ * O3_ * T_);
}

// Round 7
// 1096.253 us; speedup vs baseline: 2.7657x; 2.7657x over previous
//
#include <hip/hip_runtime.h>

#define B_   32
#define T_   300
#define C1_  2312
#define O1_  512
#define O2_  512
#define O3_  10
#define M_   (B_*T_)   // 9600
#define KSPLIT_ 1152   // gemm1 K halves: [0,1152) 288 batches, [1152,2312) 290 batches

typedef double v2d __attribute__((ext_vector_type(2)));   // clang-native vector (nontemporal OK)

// ---------------- weight prep (all f64) ----------------

__global__ void calc_f(const float* __restrict__ v, const float* __restrict__ g,
                       double* __restrict__ f, int O, int C) {
    int o = blockIdx.x;
    const float* row = v + (size_t)o * C;
    double s = 0.0;
    for (int c = threadIdx.x; c < C; c += blockDim.x) {
        double x = (double)row[c];
        s += x * x;
    }
    for (int off = 32; off; off >>= 1) s += __shfl_down(s, off);
    __shared__ double wsum[4];
    int lane = threadIdx.x & 63, wv = threadIdx.x >> 6;
    if (lane == 0) wsum[wv] = s;
    __syncthreads();
    if (threadIdx.x == 0) {
        double tot = 0.0;
        for (int i = 0; i < (int)(blockDim.x >> 6); ++i) tot += wsum[i];
        f[o] = (double)g[o] / sqrt(tot);
    }
}

// wt[c*ldo + o] = v[o*C + c] * f[o]   (double)
__global__ void transpose_scale(const float* __restrict__ v, const double* __restrict__ f,
                                double* __restrict__ wt, int O, int C, int ldo) {
    __shared__ double tile[32][33];
    int c0 = blockIdx.x * 32, o0 = blockIdx.y * 32;
    int tx = threadIdx.x, ty = threadIdx.y;
    for (int k = 0; k < 4; ++k) {
        int o = o0 + ty + k * 8, c = c0 + tx;
        double val = 0.0;
        if (o < O && c < C) val = (double)v[(size_t)o * C + c] * f[o];
        tile[ty + k * 8][tx] = val;
    }
    __syncthreads();
    for (int k = 0; k < 4; ++k) {
        int c = c0 + ty + k * 8, o = o0 + tx;
        if (c < C && o < O) wt[(size_t)c * ldo + o] = tile[tx][ty + k * 8];
    }
}

// ---------------- spike -> bitmask precompute ----------------
__global__ void build_bits(const float* __restrict__ X, unsigned* __restrict__ bits) {
    size_t idx = (size_t)blockIdx.x * 256 + threadIdx.x;
    if (idx >= (size_t)B_ * C1_ * 10) return;
    int t32 = (int)(idx % 10);
    size_t bc = idx / 10;
    const float* src = X + bc * T_ + t32 * 32;
    int nq = (t32 == 9) ? 3 : 8;   // 12 or 32 valid t's (T_=300)
    unsigned m = 0;
    for (int q = 0; q < nq; ++q) {
        float4 v = *(const float4*)(src + q * 4);
        if (v.x != 0.f) m |= 1u << (q * 4 + 0);
        if (v.y != 0.f) m |= 1u << (q * 4 + 1);
        if (v.z != 0.f) m |= 1u << (q * 4 + 2);
        if (v.w != 0.f) m |= 1u << (q * 4 + 3);
    }
    bits[idx] = m;
}

// ---------------- GEMM layer 1 v7 (L2-direct, PIPELINED unconditional loads) ----------------
// Round-6 lesson: branch-gated L2 loads serialize on latency (2354 us).  v7
// loads W rows UNCONDITIONALLY in 4-row batches into ping-pong register sets;
// the next batch's loads issue before the current batch's masked adds, so
// ~500 instr-cycles of compute cover L2 latency.  Wave geometry 16t x 128o
// (acc[16] v2d = 64 VGPR) halves W bytes/c vs 8t x 256o: total L2 read
// = 4864 waves x 1.16 MB = 5.6 GB -> ~165 us BW floor; no LDS, no barriers.
// combo = n&3 = (khalf, o-half): each XCD's L2 pins one 2.37 MB W slice.
// Ascending-c order within khalf + zA-then-zB combine in scan12 ->
// bit-identical to round 4 (passed, absmax 0.0).
// NOTE: prefetch batches may read a few rows past the W slice end (into the
// adjacent workspace buffer) -- mapped memory, values never used (masks 0).
__global__ __launch_bounds__(256, 4) void gemm1(const unsigned* __restrict__ Xbits,
                                                const double* __restrict__ Wt,
                                                double* __restrict__ Z0,
                                                double* __restrict__ Z1) {
    int n = blockIdx.x;
    int combo = n & 3;
    int khalf = combo & 1;
    int ohalf = combo >> 1;
    int i = n >> 2;                    // 0..319
    int twp = i % 10;                  // 32-t pair of 16-t windows
    int b = i / 10;
    int tid = threadIdx.x;
    int w = tid >> 6;                  // 0..3
    int lane = tid & 63;
    int oq = ohalf * 2 + (w & 1);      // o quarter (128 o's): o = oq*128 + 2*lane(+1)
    int tw = twp * 2 + (w >> 1);       // 16-t window 0..19
    if (tw >= 19) return;              // tail waves idle (no barriers -> safe)
    int shift = __builtin_amdgcn_readfirstlane((tw & 1) * 16);
    int word = tw >> 1;                // mask word 0..9
    int cbeg = khalf ? KSPLIT_ : 0;
    int cend = khalf ? C1_ : KSPLIT_;
    const int nb = khalf ? 290 : 288;  // 4-c batches (1160 / 1152 exactly)
    double* __restrict__ Z = khalf ? Z1 : Z0;
    int o0 = oq * 128;

    v2d acc[16];
#pragma unroll
    for (int tj = 0; tj < 16; ++tj) { acc[tj][0] = 0.0; acc[tj][1] = 0.0; }

    const unsigned* xbp = Xbits + (size_t)b * C1_ * 10 + word;
    auto load_m = [&](int c0) -> unsigned {
        int c = c0 + lane;
        return (lane < 16 && c < cend) ? xbp[(size_t)c * 10] : 0u;
    };
    const v2d* __restrict__ Wv = (const v2d*)(Wt + o0);   // row c at Wv + c*256

    auto load_batch = [&](int cb, v2d wf[4]) {
#pragma unroll
        for (int j = 0; j < 4; ++j)
            wf[j] = Wv[(size_t)(cb + j) * 256 + lane];
    };
    auto compute4 = [&](const v2d wf[4], unsigned mv, int kk) {
#pragma unroll
        for (int j = 0; j < 4; ++j) {
            unsigned smk = (unsigned)__builtin_amdgcn_readlane((int)mv, kk + j);
            unsigned s16 = (smk >> shift) & 0xffffu;
            if (s16) {                                   // wave-uniform scalar branch
#pragma unroll
                for (int nib = 0; nib < 4; ++nib) {
                    if (s16 & (0xfu << (nib * 4))) {     // nibble skip
#pragma unroll
                        for (int e = 0; e < 4; ++e) {
                            int tj = nib * 4 + e;
                            if (s16 & (1u << tj)) acc[tj] += wf[j];
                        }
                    }
                }
            }
        }
    };

    unsigned mval = load_m(cbeg);
    unsigned mnext = load_m(cbeg + 16);
    v2d wfa[4], wfb[4];
    load_batch(cbeg, wfa);
    for (int bt = 0; bt < nb; bt += 2) {
        int c0 = cbeg + bt * 4;
        load_batch(c0 + 4, wfb);       // prefetch batch bt+1 (unconditional)
        int kk = (bt & 3) * 4;         // 0 or 8
        compute4(wfa, mval, kk);
        load_batch(c0 + 8, wfa);       // prefetch batch bt+2 (OOB-row safe)
        compute4(wfb, mval, kk + 4);
        if (kk == 8) {                 // finished 16-c mask group
            mval = mnext;
            mnext = load_m(c0 + 24);   // group g+2 (guarded)
        }
    }
#pragma unroll
    for (int tj = 0; tj < 16; ++tj) {
        int t = tw * 16 + tj;
        if (t < T_) {
            v2d* dst = (v2d*)(Z + ((size_t)b * T_ + t) * O1_ + o0);
            __builtin_nontemporal_store(acc[tj], dst + lane);
        }
    }
}

// ---------------- GEMM layer 2 sparse (512-thr, dbuf 1-barrier, K=2 partials) ----------------
// Round-4 version (part of the 794 us best config) -- unchanged.
__global__ __launch_bounds__(512, 4) void gemm2s(const unsigned* __restrict__ Sbits,
                                                 const double* __restrict__ Wt,
                                                 double* __restrict__ Z0,
                                                 double* __restrict__ Z1) {
    __shared__ double Ws[2][16][256];   // 64 KB
    int n = blockIdx.x;
    int combo = n & 3;
    int khalf = combo & 1;
    int o0 = (combo >> 1) * 256;
    int i = n >> 2;                  // 0..159
    int twin = i % 5;                // 64-t window
    int b = i / 5;
    int tid = threadIdx.x;
    int w = tid >> 6;                // 0..7
    int lane = tid & 63;
    int w8s = __builtin_amdgcn_readfirstlane((w & 3) << 3);
    int word = twin * 2 + (w >> 2);  // which u32 of the 10 holds this octet
    int cbeg = khalf * 256;
    double* __restrict__ Z = khalf ? Z1 : Z0;
    double acc[8][4];
#pragma unroll
    for (int tj = 0; tj < 8; ++tj)
#pragma unroll
        for (int i2 = 0; i2 < 4; ++i2) acc[tj][i2] = 0.0;
    const unsigned* xbp = Sbits + (size_t)b * O1_ * 10 + word;

    double2 wreg[4];
    unsigned mval, mvaln = 0u;

    auto load_w = [&](int c0) {
#pragma unroll
        for (int h = 0; h < 4; ++h) {
            int idx = h * 512 + tid;
            int r = idx >> 7, od = (idx & 127) * 2;
            int c = c0 + r;
            wreg[h] = *(const double2*)(Wt + (size_t)c * O2_ + o0 + od);
        }
    };
    auto load_m = [&](int c0) -> unsigned {
        int c = c0 + lane;
        return (lane < 16) ? xbp[(size_t)c * 10] : 0u;
    };
    auto store_w = [&](int bi) {
#pragma unroll
        for (int h = 0; h < 4; ++h) {
            int idx = h * 512 + tid;
            int r = idx >> 7, od = (idx & 127) * 2;
            *(double2*)(&Ws[bi][r][od]) = wreg[h];
        }
    };

    load_w(cbeg);
    mval = load_m(cbeg);
    store_w(0);
    __syncthreads();
    int cur = 0;
    for (int tile = 0; tile < 16; ++tile) {
        if (tile + 1 < 16) {
            int cn = cbeg + (tile + 1) * 16;
            load_w(cn);
            mvaln = load_m(cn);
        }
#pragma unroll
        for (int k = 0; k < 16; ++k) {
            unsigned smk = (unsigned)__builtin_amdgcn_readlane((int)mval, k);
            unsigned soct = (smk >> w8s) & 0xffu;
            if (soct) {
                double wf[4];
#pragma unroll
                for (int i2 = 0; i2 < 4; ++i2) wf[i2] = Ws[cur][k][lane + 64 * i2];
#pragma unroll
                for (int tj = 0; tj < 8; ++tj) {
                    if (soct & (1u << tj)) {
#pragma unroll
                        for (int i2 = 0; i2 < 4; ++i2) acc[tj][i2] += wf[i2];
                    }
                }
            }
        }
        if (tile + 1 < 16) {
            store_w(cur ^ 1);
            __syncthreads();
        }
        mval = mvaln;
        cur ^= 1;
    }
#pragma unroll
    for (int tj = 0; tj < 8; ++tj) {
        int t = twin * 64 + w * 8 + tj;
        if (t < T_) {
            double* dst = Z + ((size_t)b * T_ + t) * O2_ + o0;
#pragma unroll
            for (int i2 = 0; i2 < 4; ++i2)
                dst[lane + 64 * i2] = acc[tj][i2];
        }
    }
}

// ---------------- GEMM layer 3 (f64 acc) ----------------
__global__ void gemm3(const float* __restrict__ A,
                      const double* __restrict__ Wt,
                      double* __restrict__ Z) {
    __shared__ double w[512 * 16];
    for (int e = threadIdx.x; e < 4096; e += 256)
        ((double2*)w)[e] = ((const double2*)Wt)[e];
    __syncthreads();
    int m = blockIdx.x * 256 + threadIdx.x;
    if (m >= M_) return;
    double acc[O3_];
#pragma unroll
    for (int o = 0; o < O3_; ++o) acc[o] = 0.0;
    const float4* Ar = (const float4*)(A + (size_t)m * 512);
    for (int cq = 0; cq < 128; ++cq) {
        float4 a = Ar[cq];
        float av[4] = {a.x, a.y, a.z, a.w};
#pragma unroll
        for (int u = 0; u < 4; ++u)
#pragma unroll
            for (int o = 0; o < O3_; ++o) acc[o] += (double)av[u] * w[(cq * 4 + u) * 16 + o];
    }
    double* dst = Z + (size_t)m * 16;
#pragma unroll
    for (int o = 0; o < O3_; ++o) dst[o] = acc[o];
}

// ---------------- LIF scan + delay, layers 1/2 (O=512, f64 state) ----------------
__global__ void scan12(const double* __restrict__ Za,   // [B, T, 512] f64
                       const double* __restrict__ Zb,   // partial 2 or nullptr
                       const int* __restrict__ delay,   // [512]
                       float* __restrict__ Sout,        // [B, T, 512] f32 or nullptr
                       unsigned* __restrict__ bitsOut,  // [B, 512, 10] u32 or nullptr
                       float* __restrict__ sumOut) {
    int blk = blockIdx.x;
    int o = (blk & 7) * 64 + threadIdx.x;
    int b = blk >> 3;
    size_t base = (size_t)b * T_ * O1_ + o;
    const double* z  = Za + base;
    const double* z2 = Zb ? Zb + base : nullptr;
    float* s = Sout ? Sout + base : nullptr;
    int d = delay[o];
    if (s) for (int t = 0; t < d; ++t) s[(size_t)t * O1_] = 0.f;
    double cur = 0.0, vol = 0.0;
    float cnt = 0.f;
    unsigned bw = 0u;   // running bit word; d<32 so words 0..8 flush in-loop
    for (int t8 = 0; t8 < 296; t8 += 8) {
        double zbuf[8];
#pragma unroll
        for (int u = 0; u < 8; ++u) zbuf[u] = z[(size_t)(t8 + u) * O1_];
        if (z2) {
#pragma unroll
            for (int u = 0; u < 8; ++u) zbuf[u] += z2[(size_t)(t8 + u) * O1_];
        }
#pragma unroll
        for (int u = 0; u < 8; ++u) {
            int t = t8 + u;
            cur = cur * 0.75 + zbuf[u];
            vol = vol * 0.97 + cur;
            float sp = (vol >= 1.25) ? 1.f : 0.f;
            if (sp > 0.f) vol = 0.0;
            int tw = t + d;
            if (tw < T_) {
                if (s) s[(size_t)tw * O1_] = sp;
                cnt += sp;
                if (bitsOut) {
                    if (sp > 0.f) bw |= 1u << (tw & 31);
                    if ((tw & 31) == 31) { bitsOut[((size_t)b * O1_ + o) * 10 + (tw >> 5)] = bw; bw = 0u; }
                }
            }
        }
    }
    {
        double zbuf[4];
#pragma unroll
        for (int u = 0; u < 4; ++u) zbuf[u] = z[(size_t)(296 + u) * O1_];
        if (z2) {
#pragma unroll
            for (int u = 0; u < 4; ++u) zbuf[u] += z2[(size_t)(296 + u) * O1_];
        }
#pragma unroll
        for (int u = 0; u < 4; ++u) {
            int t = 296 + u;
            cur = cur * 0.75 + zbuf[u];
            vol = vol * 0.97 + cur;
            float sp = (vol >= 1.25) ? 1.f : 0.f;
            if (sp > 0.f) vol = 0.0;
            int tw = t + d;
            if (tw < T_) {
                if (s) s[(size_t)tw * O1_] = sp;
                cnt += sp;
                if (bitsOut) {
                    if (sp > 0.f) bw |= 1u << (tw & 31);
                    if ((tw & 31) == 31) { bitsOut[((size_t)b * O1_ + o) * 10 + (tw >> 5)] = bw; bw = 0u; }
                }
            }
        }
    }
    if (bitsOut) bitsOut[((size_t)b * O1_ + o) * 10 + 9] = bw;  // word 9 never flushes in-loop
    for (int off = 32; off; off >>= 1) cnt += __shfl_down(cnt, off);
    if (threadIdx.x == 0) atomicAdd(sumOut, cnt);
}

// ---------------- LIF scan + delay, layer 3 (O=10, f64 state) ----------------
__global__ void scan3(const double* __restrict__ Z3,  // [M, 16] f64
                      const int* __restrict__ d3,     // [10]
                      float* __restrict__ out,        // d_out: [B, 10, 300] f32
                      float* __restrict__ sumOut) {
    __shared__ double zt[T_ * 16];
    int b = blockIdx.x;
    const double2* src = (const double2*)(Z3 + (size_t)b * T_ * 16);
    for (int e = threadIdx.x; e < T_ * 8; e += 64)
        ((double2*)zt)[e] = src[e];
    __syncthreads();
    int o = threadIdx.x;
    if (o < O3_) {
        int d = d3[o];
        float* dst = out + (size_t)b * O3_ * T_ + (size_t)o * T_;
        for (int t = 0; t < d; ++t) dst[t] = 0.f;
        double cur = 0.0, vol = 0.0;
        float cnt = 0.f;
        for (int t = 0; t < T_; ++t) {
            cur = cur * 0.75 + zt[t * 16 + o];
            vol = vol * 0.97 + cur;
            float sp = (vol >= 1.25) ? 1.f : 0.f;
            if (sp > 0.f) vol = 0.0;
            int tw = t + d;
            if (tw < T_) { dst[tw] = sp; cnt += sp; }
        }
        atomicAdd(sumOut, cnt);
    }
}

__global__ void finalize(const float* __restrict__ sums, float* __restrict__ out) {
    if (threadIdx.x == 0) {
        out[0] = (float)((double)sums[0] / (double)(B_ * O1_ * T_));
        out[1] = (float)((double)sums[1] / (double)(B_ * O2_ * T_));
        out[2] = (float)((double)sums[2] / (double)(B_ * O3_ * T_));
    }
}

extern "C" void kernel_launch(void* const* d_in, const int* in_sizes, int n_in,
                              void* d_out, int out_size, void* d_ws, size_t ws_size,
                              hipStream_t stream) {
    const float* spike = (const float*)d_in[0];
    const float* v1 = (const float*)d_in[1];
    const float* g1 = (const float*)d_in[2];
    const float* v2 = (const float*)d_in[3];
    const float* g2 = (const float*)d_in[4];
    const float* v3 = (const float*)d_in[5];
    const float* g3 = (const float*)d_in[6];
    const int* d1 = (const int*)d_in[7];
    const int* d2 = (const int*)d_in[8];
    const int* d3 = (const int*)d_in[9];
    float* out = (float*)d_out;

    // Workspace: ~115 MB (round-4 layout).
    double* dw = (double*)d_ws;
    size_t off = 0;
    double* f1  = dw + off; off += 512;
    double* f2  = dw + off; off += 512;
    double* f3  = dw + off; off += 16;
    double* Wt1 = dw + off; off += (size_t)C1_ * O1_;
    double* Wt2 = dw + off; off += 512 * 512;
    double* Wt3 = dw + off; off += 512 * 16;
    double* zA  = dw + off; off += (size_t)M_ * 512;
    double* zB  = dw + off; off += (size_t)M_ * 512;
    double* z3b = dw + off; off += (size_t)M_ * 16;
    float* fw = (float*)(dw + off);
    float* sB    = fw;                                   // f32 spikes, M*512
    float* sums  = fw + (size_t)M_ * 512;                // 4 floats
    unsigned* Xbits = (unsigned*)(fw + (size_t)M_ * 512 + 4);  // B*C1*10 u32
    unsigned* bits2 = Xbits + (size_t)B_ * C1_ * 10;           // B*512*10 u32
    (void)ws_size; (void)out_size; (void)in_sizes; (void)n_in;

    hipMemsetAsync(sums, 0, 4 * sizeof(float), stream);

    build_bits<<<(B_ * C1_ * 10 + 255) / 256, 256, 0, stream>>>(spike, Xbits);

    calc_f<<<512, 256, 0, stream>>>(v1, g1, f1, O1_, C1_);
    calc_f<<<512, 256, 0, stream>>>(v2, g2, f2, O2_, O1_);
    calc_f<<<O3_, 256, 0, stream>>>(v3, g3, f3, O3_, O2_);

    transpose_scale<<<dim3((C1_ + 31) / 32, 16), dim3(32, 8), 0, stream>>>(v1, f1, Wt1, O1_, C1_, O1_);
    transpose_scale<<<dim3(16, 16), dim3(32, 8), 0, stream>>>(v2, f2, Wt2, O2_, O1_, O2_);
    transpose_scale<<<dim3(16, 1), dim3(32, 8), 0, stream>>>(v3, f3, Wt3, O3_, O2_, 16);

    // gemm1 v7: 1280 blocks x 256 thr, pipelined L2-direct, no barriers
    gemm1<<<1280, 256, 0, stream>>>(Xbits, Wt1, zA, zB);
    // scan12 #1: sum zA+zB, emit ONLY bits (s1 floats are dead)
    scan12<<<256, 64, 0, stream>>>(zA, zB, d1, nullptr, bits2, sums + 0);
    // gemm2s (round-4 dbuf): 640 blocks x 512 thr, K=2 plain partials
    gemm2s<<<640, 512, 0, stream>>>(bits2, Wt2, zA, zB);
    // scan12 #2: sum zA+zB, emit ONLY floats (bits are dead)
    scan12<<<256, 64, 0, stream>>>(zA, zB, d2, sB, nullptr, sums + 1);
    gemm3<<<(M_ + 255) / 256, 256, 0, stream>>>(sB, Wt3, z3b);        // z3b = z3
    scan3<<<B_, 64, 0, stream>>>(z3b, d3, out, sums + 2);
    finalize<<<1, 64, 0, stream>>>(sums, out + (size_t)B_ * O3_ * T_);
}